// Round 1
// baseline (82.709 us; speedup 1.0000x reference)
//
#include <hip/hip_runtime.h>
#include <math.h>

// ---------------------------------------------------------------------------
// RegressionLoss: chamfer(32x32 shape pairs of 256 3D pts) -> softmax vs
// normalized-embedding inner-product softmax -> mean |p_hat - p|.
// Inputs: d_in[0] = embeddings (64x512 f32), d_in[1] = xyz (64x256x3 f32).
// Output: d_out[0] single f32.
// ---------------------------------------------------------------------------

__device__ __forceinline__ float waveReduceSum64(float v) {
    #pragma unroll
    for (int m = 32; m > 0; m >>= 1) v += __shfl_xor(v, m, 64);
    return v;
}

// blocks 0..527: chamfer for upper-triangle pair (i<=j), writes cd[i][j] and cd[j][i]
// blocks 528..559: row i of normalized inner_dot (32x32)
__global__ __launch_bounds__(256) void pairs_kernel(const float* __restrict__ emb,
                                                    const float* __restrict__ xyz,
                                                    float* __restrict__ cd,
                                                    float* __restrict__ dots) {
    const int t = threadIdx.x;
    const int b = blockIdx.x;

    __shared__ float4 SA[256];   // shape i points (x,y,z,0)
    __shared__ float4 SB[256];   // shape j points
    __shared__ float  red[16];

    if (b < 528) {
        // triangular decode: row i has (32-i) entries, j = i..31
        int i = 0, rem = b;
        while (rem >= (32 - i)) { rem -= (32 - i); ++i; }
        const int j = i + rem;

        const float* Pi = xyz + (32 + i) * 768;   // shapes = xyz[32:]
        const float* Pj = xyz + (32 + j) * 768;

        SA[t] = make_float4(Pi[3*t], Pi[3*t+1], Pi[3*t+2], 0.0f);
        SB[t] = make_float4(Pj[3*t], Pj[3*t+1], Pj[3*t+2], 0.0f);
        __syncthreads();

        const float4 P = SA[t];   // my point of shape i (role: p)
        const float4 Q = SB[t];   // my point of shape j (role: q)
        float minA = 3.4e38f;     // min_q d2(P, j_q)
        float minB = 3.4e38f;     // min_p d2(i_p, Q)
        #pragma unroll 8
        for (int s = 0; s < 256; ++s) {
            const float4 a  = SA[s];   // broadcast reads (uniform addr)
            const float4 bb = SB[s];
            float dx = P.x - bb.x, dy = P.y - bb.y, dz = P.z - bb.z;
            float dA = dx*dx + dy*dy + dz*dz;
            float ex = Q.x - a.x,  ey = Q.y - a.y,  ez = Q.z - a.z;
            float dB = ex*ex + ey*ey + ez*ez;
            minA = fminf(minA, dA);
            minB = fminf(minB, dB);
        }

        float v = waveReduceSum64(minA + minB);
        if ((t & 63) == 0) red[t >> 6] = v;
        __syncthreads();
        if (t == 0) {
            float s = (red[0] + red[1] + red[2] + red[3]) * (1.0f / 256.0f);
            cd[i * 32 + j] = s;
            cd[j * 32 + i] = s;   // chamfer is symmetric in (i,j)
        }
    } else {
        const int i = b - 528;    // sketch row 0..31
        // stage sketch row i in LDS (reuse SA/SB storage via separate array is
        // unnecessary; reuse SA as raw floats)
        float* rowi = (float*)SA;                 // 512 floats = 2KB, fits in SA
        const float* Ei = emb + i * 512;
        rowi[t]       = Ei[t];
        rowi[t + 256] = Ei[t + 256];
        __syncthreads();

        const int w    = t >> 6;
        const int lane = t & 63;

        // norm^2 of row i (computed per-wave, redundant but cheap)
        float ni = 0.0f;
        #pragma unroll
        for (int m = 0; m < 8; ++m) { float a = rowi[lane + 64*m]; ni += a*a; }
        ni = waveReduceSum64(ni);

        // each of the 4 waves handles 8 of the 32 shape columns
        for (int j = w; j < 32; j += 4) {
            const float* Ej = emb + (32 + j) * 512;
            float dot = 0.0f, nj = 0.0f;
            #pragma unroll
            for (int m = 0; m < 8; ++m) {
                float a  = rowi[lane + 64*m];
                float bv = Ej[lane + 64*m];
                dot += a * bv;
                nj  += bv * bv;
            }
            dot = waveReduceSum64(dot);
            nj  = waveReduceSum64(nj);
            if (lane == 0) dots[i * 32 + j] = dot * rsqrtf(ni * nj);
        }
    }
}

// 1 block x 1024 threads: softmaxes + mean abs diff
__global__ __launch_bounds__(1024) void finish_kernel(const float* __restrict__ cd,
                                                      const float* __restrict__ dots,
                                                      float* __restrict__ out) {
    const int t = threadIdx.x;   // t = i*32 + j ; width-32 segments == rows
    const float inv_denom = 1.0f / (2.0f * (0.997f / 3.0f) * (0.997f / 3.0f));

    float c = cd[t];
    float s = -(c * c) * inv_denom;
    float h = dots[t];

    // softmax of s over 32-wide row segment
    float m1 = s;
    #pragma unroll
    for (int k = 16; k > 0; k >>= 1) m1 = fmaxf(m1, __shfl_xor(m1, k, 32));
    float e1 = expf(s - m1);
    float sum1 = e1;
    #pragma unroll
    for (int k = 16; k > 0; k >>= 1) sum1 += __shfl_xor(sum1, k, 32);
    float p = e1 / sum1;

    // softmax of h over row segment
    float m2 = h;
    #pragma unroll
    for (int k = 16; k > 0; k >>= 1) m2 = fmaxf(m2, __shfl_xor(m2, k, 32));
    float e2 = expf(h - m2);
    float sum2 = e2;
    #pragma unroll
    for (int k = 16; k > 0; k >>= 1) sum2 += __shfl_xor(sum2, k, 32);
    float ph = e2 / sum2;

    float a = fabsf(ph - p);
    a = waveReduceSum64(a);

    __shared__ float red[16];
    if ((t & 63) == 0) red[t >> 6] = a;
    __syncthreads();
    if (t == 0) {
        float tot = 0.0f;
        #pragma unroll
        for (int k = 0; k < 16; ++k) tot += red[k];
        out[0] = tot * (1.0f / 1024.0f);
    }
}

extern "C" void kernel_launch(void* const* d_in, const int* in_sizes, int n_in,
                              void* d_out, int out_size, void* d_ws, size_t ws_size,
                              hipStream_t stream) {
    const float* emb = (const float*)d_in[0];   // 64 x 512
    const float* xyz = (const float*)d_in[1];   // 64 x 256 x 3
    float* cd   = (float*)d_ws;                 // 32x32
    float* dots = cd + 1024;                    // 32x32
    float* out  = (float*)d_out;

    hipLaunchKernelGGL(pairs_kernel, dim3(560), dim3(256), 0, stream, emb, xyz, cd, dots);
    hipLaunchKernelGGL(finish_kernel, dim3(1), dim3(1024), 0, stream, cd, dots, out);
}

// Round 2
// 70.564 us; speedup vs baseline: 1.1721x; 1.1721x over previous
//
#include <hip/hip_runtime.h>
#include <math.h>

// ---------------------------------------------------------------------------
// RegressionLoss: chamfer(32x32 shape pairs of 256 3D pts) -> softmax vs
// normalized-embedding inner-product softmax -> mean |p_hat - p|.
// Inputs: d_in[0] = embeddings (64x512 f32), d_in[1] = xyz (64x256x3 f32).
// Output: d_out[0] single f32.
//
// R2: SoA LDS layout (1 ds_read_b128 feeds 4 s-iters, broadcast) + float2
// packed arithmetic to target v_pk_{fma,add,mul}_f32. Theory: R1 loop was
// LDS-issue-bound (~2 b128/iter); this makes it VALU-bound (~1.5 b128/4 iter).
// ---------------------------------------------------------------------------

typedef float f32x2 __attribute__((ext_vector_type(2)));

__device__ __forceinline__ float waveReduceSum64(float v) {
    #pragma unroll
    for (int m = 32; m > 0; m >>= 1) v += __shfl_xor(v, m, 64);
    return v;
}

// blocks 0..527: chamfer for upper-triangle pair (i<=j), writes cd[i][j], cd[j][i]
// blocks 528..559: row i of normalized inner_dot (32x32)
__global__ __launch_bounds__(256) void pairs_kernel(const float* __restrict__ emb,
                                                    const float* __restrict__ xyz,
                                                    float* __restrict__ cd,
                                                    float* __restrict__ dots) {
    const int t = threadIdx.x;
    const int b = blockIdx.x;

    __shared__ __align__(16) float S[6 * 256];   // SoA: Ax,Ay,Az,Bx,By,Bz
    __shared__ float red[4];
    float* SAx = S;
    float* SAy = S + 256;
    float* SAz = S + 512;
    float* SBx = S + 768;
    float* SBy = S + 1024;
    float* SBz = S + 1280;

    if (b < 528) {
        // triangular decode: row i has (32-i) entries, j = i..31
        int i = 0, rem = b;
        while (rem >= (32 - i)) { rem -= (32 - i); ++i; }
        const int j = i + rem;

        const float* Pi = xyz + (32 + i) * 768;   // shapes = xyz[32:]
        const float* Pj = xyz + (32 + j) * 768;

        const float pax = Pi[3*t], pay = Pi[3*t+1], paz = Pi[3*t+2];
        const float pbx = Pj[3*t], pby = Pj[3*t+1], pbz = Pj[3*t+2];
        SAx[t] = pax; SAy[t] = pay; SAz[t] = paz;
        SBx[t] = pbx; SBy[t] = pby; SBz[t] = pbz;
        __syncthreads();

        // thread t: P = point t of shape i (minimize over B points),
        //           Q = point t of shape j (minimize over A points)
        const f32x2 Px = {pax, pax}, Py = {pay, pay}, Pz = {paz, paz};
        const f32x2 Qx = {pbx, pbx}, Qy = {pby, pby}, Qz = {pbz, pbz};

        f32x2 mA0 = {3.4e38f, 3.4e38f}, mA1 = {3.4e38f, 3.4e38f};
        f32x2 mB0 = {3.4e38f, 3.4e38f}, mB1 = {3.4e38f, 3.4e38f};

        #pragma unroll 2
        for (int s = 0; s < 256; s += 4) {
            const float4 ax = *(const float4*)&SAx[s];
            const float4 ay = *(const float4*)&SAy[s];
            const float4 az = *(const float4*)&SAz[s];
            const float4 bx = *(const float4*)&SBx[s];
            const float4 by = *(const float4*)&SBy[s];
            const float4 bz = *(const float4*)&SBz[s];

            {   // s, s+1
                const f32x2 vbx = {bx.x, bx.y}, vby = {by.x, by.y}, vbz = {bz.x, bz.y};
                f32x2 dx = Px - vbx, dy = Py - vby, dz = Pz - vbz;
                f32x2 d = dx*dx + dy*dy + dz*dz;
                mA0.x = fminf(mA0.x, d.x); mA0.y = fminf(mA0.y, d.y);
                const f32x2 vax = {ax.x, ax.y}, vay = {ay.x, ay.y}, vaz = {az.x, az.y};
                f32x2 ex = Qx - vax, ey = Qy - vay, ez = Qz - vaz;
                f32x2 e = ex*ex + ey*ey + ez*ez;
                mB0.x = fminf(mB0.x, e.x); mB0.y = fminf(mB0.y, e.y);
            }
            {   // s+2, s+3
                const f32x2 vbx = {bx.z, bx.w}, vby = {by.z, by.w}, vbz = {bz.z, bz.w};
                f32x2 dx = Px - vbx, dy = Py - vby, dz = Pz - vbz;
                f32x2 d = dx*dx + dy*dy + dz*dz;
                mA1.x = fminf(mA1.x, d.x); mA1.y = fminf(mA1.y, d.y);
                const f32x2 vax = {ax.z, ax.w}, vay = {ay.z, ay.w}, vaz = {az.z, az.w};
                f32x2 ex = Qx - vax, ey = Qy - vay, ez = Qz - vaz;
                f32x2 e = ex*ex + ey*ey + ez*ez;
                mB1.x = fminf(mB1.x, e.x); mB1.y = fminf(mB1.y, e.y);
            }
        }

        const float minA = fminf(fminf(mA0.x, mA0.y), fminf(mA1.x, mA1.y));
        const float minB = fminf(fminf(mB0.x, mB0.y), fminf(mB1.x, mB1.y));

        float v = waveReduceSum64(minA + minB);
        if ((t & 63) == 0) red[t >> 6] = v;
        __syncthreads();
        if (t == 0) {
            float s = (red[0] + red[1] + red[2] + red[3]) * (1.0f / 256.0f);
            cd[i * 32 + j] = s;
            cd[j * 32 + i] = s;   // chamfer is symmetric in (i,j)
        }
    } else {
        const int i = b - 528;    // sketch row 0..31
        float* rowi = S;          // 512 floats
        const float* Ei = emb + i * 512;
        rowi[t]       = Ei[t];
        rowi[t + 256] = Ei[t + 256];
        __syncthreads();

        const int w    = t >> 6;
        const int lane = t & 63;

        // norm^2 of sketch row i (redundant per wave, cheap)
        float ni = 0.0f;
        #pragma unroll
        for (int m = 0; m < 8; ++m) { float a = rowi[lane + 64*m]; ni += a*a; }
        ni = waveReduceSum64(ni);

        // 4 waves x 8 shape columns each
        for (int j = w; j < 32; j += 4) {
            const float* Ej = emb + (32 + j) * 512;
            float dot = 0.0f, nj = 0.0f;
            #pragma unroll
            for (int m = 0; m < 8; ++m) {
                float a  = rowi[lane + 64*m];
                float bv = Ej[lane + 64*m];
                dot += a * bv;
                nj  += bv * bv;
            }
            dot = waveReduceSum64(dot);
            nj  = waveReduceSum64(nj);
            if (lane == 0) dots[i * 32 + j] = dot * rsqrtf(ni * nj);
        }
    }
}

// 1 block x 1024 threads: softmaxes + mean abs diff
__global__ __launch_bounds__(1024) void finish_kernel(const float* __restrict__ cd,
                                                      const float* __restrict__ dots,
                                                      float* __restrict__ out) {
    const int t = threadIdx.x;   // t = i*32 + j ; width-32 segments == rows
    const float inv_denom = 1.0f / (2.0f * (0.997f / 3.0f) * (0.997f / 3.0f));

    float c = cd[t];
    float s = -(c * c) * inv_denom;
    float h = dots[t];

    float m1 = s;
    #pragma unroll
    for (int k = 16; k > 0; k >>= 1) m1 = fmaxf(m1, __shfl_xor(m1, k, 32));
    float e1 = expf(s - m1);
    float sum1 = e1;
    #pragma unroll
    for (int k = 16; k > 0; k >>= 1) sum1 += __shfl_xor(sum1, k, 32);
    float p = e1 / sum1;

    float m2 = h;
    #pragma unroll
    for (int k = 16; k > 0; k >>= 1) m2 = fmaxf(m2, __shfl_xor(m2, k, 32));
    float e2 = expf(h - m2);
    float sum2 = e2;
    #pragma unroll
    for (int k = 16; k > 0; k >>= 1) sum2 += __shfl_xor(sum2, k, 32);
    float ph = e2 / sum2;

    float a = fabsf(ph - p);
    a = waveReduceSum64(a);

    __shared__ float red[16];
    if ((t & 63) == 0) red[t >> 6] = a;
    __syncthreads();
    if (t == 0) {
        float tot = 0.0f;
        #pragma unroll
        for (int k = 0; k < 16; ++k) tot += red[k];
        out[0] = tot * (1.0f / 1024.0f);
    }
}

extern "C" void kernel_launch(void* const* d_in, const int* in_sizes, int n_in,
                              void* d_out, int out_size, void* d_ws, size_t ws_size,
                              hipStream_t stream) {
    const float* emb = (const float*)d_in[0];   // 64 x 512
    const float* xyz = (const float*)d_in[1];   // 64 x 256 x 3
    float* cd   = (float*)d_ws;                 // 32x32
    float* dots = cd + 1024;                    // 32x32
    float* out  = (float*)d_out;

    hipLaunchKernelGGL(pairs_kernel, dim3(560), dim3(256), 0, stream, emb, xyz, cd, dots);
    hipLaunchKernelGGL(finish_kernel, dim3(1), dim3(1024), 0, stream, cd, dots, out);
}

// Round 3
// 66.218 us; speedup vs baseline: 1.2490x; 1.0656x over previous
//
#include <hip/hip_runtime.h>
#include <math.h>

// ---------------------------------------------------------------------------
// RegressionLoss: chamfer(32x32 shape pairs of 256 3D pts) -> softmax vs
// normalized-embedding inner-product softmax -> mean |p_hat - p|.
// Inputs: d_in[0] = embeddings (64x512 f32), d_in[1] = xyz (64x256x3 f32).
// Output: d_out[0] single f32.
//
// R3: direction-split chamfer. cd[i][i]==0 (skip diagonal), each off-diag
// pair (i<j) -> 2 blocks (one per direction). 496*2 + 32 dot rows = 1024
// blocks = exactly 4/CU (perfect balance; R2 had 2.19/CU -> 1.37x tail).
// Outer point lives in regs (global read), only inner shape in LDS SoA ->
// 3 broadcast ds_read_b128 per 4 inner points. Packed f32x2 arithmetic.
// ---------------------------------------------------------------------------

typedef float f32x2 __attribute__((ext_vector_type(2)));

__device__ __forceinline__ float waveReduceSum64(float v) {
    #pragma unroll
    for (int m = 32; m > 0; m >>= 1) v += __shfl_xor(v, m, 64);
    return v;
}

// blocks [0,992): directional chamfer half. pb=b>>1 indexes strict upper
//   triangle (i<j) of 32; dir=b&1. Writes cdHalf[b] = mean_p min_q d2.
// blocks [992,1024): dot row i=b-992 -> dots[i*32+j], j=0..31.
__global__ __launch_bounds__(256) void pairs_kernel(const float* __restrict__ emb,
                                                    const float* __restrict__ xyz,
                                                    float* __restrict__ cdHalf,
                                                    float* __restrict__ dots) {
    const int t = threadIdx.x;
    const int b = blockIdx.x;

    __shared__ __align__(16) float S[3 * 256];   // inner shape SoA: x,y,z
    __shared__ float red[4];
    float* Sx = S;
    float* Sy = S + 256;
    float* Sz = S + 512;

    if (b < 992) {
        const int pb  = b >> 1;
        const int dir = b & 1;
        // strict-upper-triangle decode: row i has (31-i) entries
        int i = 0, rem = pb;
        while (rem >= (31 - i)) { rem -= (31 - i); ++i; }
        const int j = i + 1 + rem;

        const int outer = dir ? j : i;
        const int inner = dir ? i : j;

        const float* Po = xyz + (32 + outer) * 768;   // shapes = xyz[32:]
        const float* Pi = xyz + (32 + inner) * 768;

        // stage inner shape into LDS SoA
        const float ix = Pi[3*t], iy = Pi[3*t+1], iz = Pi[3*t+2];
        Sx[t] = ix; Sy[t] = iy; Sz[t] = iz;
        // my outer point
        const float px = Po[3*t], py = Po[3*t+1], pz = Po[3*t+2];
        __syncthreads();

        const f32x2 Px = {px, px}, Py = {py, py}, Pz = {pz, pz};
        f32x2 m0 = {3.4e38f, 3.4e38f}, m1 = {3.4e38f, 3.4e38f};

        #pragma unroll 4
        for (int s = 0; s < 256; s += 4) {
            const float4 vx = *(const float4*)&Sx[s];   // broadcast b128
            const float4 vy = *(const float4*)&Sy[s];
            const float4 vz = *(const float4*)&Sz[s];
            {   // s, s+1
                const f32x2 bx = {vx.x, vx.y}, by = {vy.x, vy.y}, bz = {vz.x, vz.y};
                f32x2 dx = Px - bx, dy = Py - by, dz = Pz - bz;
                f32x2 d = dx*dx + dy*dy + dz*dz;
                m0.x = fminf(m0.x, d.x); m0.y = fminf(m0.y, d.y);
            }
            {   // s+2, s+3
                const f32x2 bx = {vx.z, vx.w}, by = {vy.z, vy.w}, bz = {vz.z, vz.w};
                f32x2 dx = Px - bx, dy = Py - by, dz = Pz - bz;
                f32x2 d = dx*dx + dy*dy + dz*dz;
                m1.x = fminf(m1.x, d.x); m1.y = fminf(m1.y, d.y);
            }
        }
        const float mn = fminf(fminf(m0.x, m0.y), fminf(m1.x, m1.y));

        float v = waveReduceSum64(mn);
        if ((t & 63) == 0) red[t >> 6] = v;
        __syncthreads();
        if (t == 0)
            cdHalf[b] = (red[0] + red[1] + red[2] + red[3]) * (1.0f / 256.0f);
    } else {
        const int i = b - 992;    // sketch row 0..31
        float* rowi = S;          // 512 floats (fits in 768-float S)
        const float* Ei = emb + i * 512;
        rowi[t]       = Ei[t];
        rowi[t + 256] = Ei[t + 256];
        __syncthreads();

        const int w    = t >> 6;
        const int lane = t & 63;

        // norm^2 of sketch row i (redundant per wave, cheap)
        float ni = 0.0f;
        #pragma unroll
        for (int m = 0; m < 8; ++m) { float a = rowi[lane + 64*m]; ni += a*a; }
        ni = waveReduceSum64(ni);

        // 4 waves x 8 shape columns each
        for (int j = w; j < 32; j += 4) {
            const float* Ej = emb + (32 + j) * 512;
            float dot = 0.0f, nj = 0.0f;
            #pragma unroll
            for (int m = 0; m < 8; ++m) {
                float a  = rowi[lane + 64*m];
                float bv = Ej[lane + 64*m];
                dot += a * bv;
                nj  += bv * bv;
            }
            dot = waveReduceSum64(dot);
            nj  = waveReduceSum64(nj);
            if (lane == 0) dots[i * 32 + j] = dot * rsqrtf(ni * nj);
        }
    }
}

// 1 block x 1024 threads: assemble cd, softmaxes, mean abs diff
__global__ __launch_bounds__(1024) void finish_kernel(const float* __restrict__ cdHalf,
                                                      const float* __restrict__ dots,
                                                      float* __restrict__ out) {
    const int t = threadIdx.x;   // t = i*32 + j ; width-32 segments == rows
    const int i = t >> 5;
    const int j = t & 31;
    const float inv_denom = 1.0f / (2.0f * (0.997f / 3.0f) * (0.997f / 3.0f));

    float c;
    if (i == j) {
        c = 0.0f;                 // chamfer(self) == 0 (min includes q=p)
    } else {
        const int a  = min(i, j), bb = max(i, j);
        const int pb = a * 31 - (a * (a - 1)) / 2 + (bb - a - 1);
        c = cdHalf[2 * pb] + cdHalf[2 * pb + 1];
    }
    float s = -(c * c) * inv_denom;
    float h = dots[t];

    float m1 = s;
    #pragma unroll
    for (int k = 16; k > 0; k >>= 1) m1 = fmaxf(m1, __shfl_xor(m1, k, 32));
    float e1 = expf(s - m1);
    float sum1 = e1;
    #pragma unroll
    for (int k = 16; k > 0; k >>= 1) sum1 += __shfl_xor(sum1, k, 32);
    float p = e1 / sum1;

    float m2 = h;
    #pragma unroll
    for (int k = 16; k > 0; k >>= 1) m2 = fmaxf(m2, __shfl_xor(m2, k, 32));
    float e2 = expf(h - m2);
    float sum2 = e2;
    #pragma unroll
    for (int k = 16; k > 0; k >>= 1) sum2 += __shfl_xor(sum2, k, 32);
    float ph = e2 / sum2;

    float a = fabsf(ph - p);
    a = waveReduceSum64(a);

    __shared__ float red[16];
    if ((t & 63) == 0) red[t >> 6] = a;
    __syncthreads();
    if (t == 0) {
        float tot = 0.0f;
        #pragma unroll
        for (int k = 0; k < 16; ++k) tot += red[k];
        out[0] = tot * (1.0f / 1024.0f);
    }
}

extern "C" void kernel_launch(void* const* d_in, const int* in_sizes, int n_in,
                              void* d_out, int out_size, void* d_ws, size_t ws_size,
                              hipStream_t stream) {
    const float* emb = (const float*)d_in[0];   // 64 x 512
    const float* xyz = (const float*)d_in[1];   // 64 x 256 x 3
    float* cdHalf = (float*)d_ws;               // 992 directional halves
    float* dots   = cdHalf + 1024;              // 32x32
    float* out    = (float*)d_out;

    hipLaunchKernelGGL(pairs_kernel, dim3(1024), dim3(256), 0, stream, emb, xyz, cdHalf, dots);
    hipLaunchKernelGGL(finish_kernel, dim3(1), dim3(1024), 0, stream, cdHalf, dots, out);
}